// Round 1
// baseline (876.340 us; speedup 1.0000x reference)
//
#include <hip/hip_runtime.h>
#include <math.h>

#define KTOT 4096
#define BNUM 64
#define MNUM 64

__device__ const float c_cls_mean[3][3] = {
    {1.76255119f, 0.66068622f, 0.84422524f},
    {1.52563191462f, 1.62856739989f, 3.88311640418f},
    {1.73698127f, 0.59706367f, 1.76282397f}
};

// Compute the 5 Qpred (x,z) points for element k under combo c.
// Geometry in f32 (matches the JAX reference's f32 arithmetic).
__device__ __forceinline__ void compute_qpred(
    int k, int combo,
    const float* __restrict__ center, const int* __restrict__ cls_ids,
    const float* __restrict__ ry, const float* __restrict__ size3d,
    const float* __restrict__ off_gt, const float* __restrict__ dep_gt,
    const float* __restrict__ out_off, const float* __restrict__ out_dep,
    const float* __restrict__ calibs, const float* __restrict__ trans_inv,
    float* qx, float* qz)
{
    const int b = k >> 6;
    const float cx = center[2*k], cy = center[2*k+1];
    const int cid = cls_ids[k];
    const float d0 = size3d[3*k+0] + c_cls_mean[cid][0];
    const float d1 = size3d[3*k+1] + c_cls_mean[cid][1];
    const float d2 = size3d[3*k+2] + c_cls_mean[cid][2];
    float sn, cs;
    sincosf(ry[k], &sn, &cs);

    const float* C = calibs + b*12;
    const float f  = C[0];     // calib[0,0] == calib[1,1]
    const float cu = C[2];
    const float tx = C[3];
    const float cv = C[6];
    const float t_x = -tx / f; // t = (calib[0,3]/-f, 0)

    const float* TI = trans_inv + b*6;
    const float s   = TI[0];
    const float t0x = TI[2];
    const float t0y = TI[5];

    float ox, oy, dep;
    if (combo == 0)      { ox = off_gt[2*k];  oy = off_gt[2*k+1];  dep = out_dep[k]; }
    else if (combo == 1) { ox = out_off[2*k]; oy = out_off[2*k+1]; dep = dep_gt[k]; }
    else                 { ox = out_off[2*k]; oy = out_off[2*k+1]; dep = out_dep[k]; }

    const float uv4x = (cx + ox) * 4.0f;
    const float uv4y = (cy + oy) * 4.0f;
    const float projx = s * uv4x + t0x;
    const float projy = s * uv4y + t0y;
    const float px = (projx - cu) * dep / f + t_x;
    (void)projy; (void)cv; // y-coordinate never feeds x/z outputs
    const float Px = px;
    const float Pz = dep;

    // c5 point 0 = origin; points 1..4 = rotated corners (y-components unused)
    // scaled col n (n<4): (d2*r2[n], 0, d1*r1[n]);  x' = cs*sx + sn*sz ; z' = -sn*sx + cs*sz
    const float r1t[4] = {0.5f, -0.5f, -0.5f, 0.5f};
    const float r2t[4] = {0.5f,  0.5f, -0.5f, -0.5f};
    qx[0] = Px; qz[0] = Pz;
    #pragma unroll
    for (int n = 0; n < 4; ++n) {
        const float sx = d2 * r2t[n];
        const float sz = d1 * r1t[n];
        qx[n+1] = Px + (cs*sx + sn*sz);
        qz[n+1] = Pz + (-sn*sx + cs*sz);
    }
}

__device__ __forceinline__ double sl1(double p, double t) {
    double d = p - t, ad = fabs(d);
    return ad < 1.0 ? 0.5*d*d : ad - 0.5;
}

// One wave per (batch, combo): accumulate 9x9 Gram (upper tri, 45 entries) in double.
__global__ __launch_bounds__(64) void gram_kernel(
    const float* __restrict__ center, const int* __restrict__ cls_ids,
    const float* __restrict__ ry, const float* __restrict__ size3d,
    const float* __restrict__ Pgt,
    const float* __restrict__ off_gt, const float* __restrict__ dep_gt,
    const float* __restrict__ out_off, const float* __restrict__ out_dep,
    const float* __restrict__ calibs, const float* __restrict__ trans_inv,
    double* __restrict__ gram)
{
    const int b = blockIdx.x, combo = blockIdx.y;
    const int m = threadIdx.x;
    const int k = (b << 6) + m;

    float qx[5], qz[5];
    compute_qpred(k, combo, center, cls_ids, ry, size3d,
                  off_gt, dep_gt, out_off, out_dep, calibs, trans_inv, qx, qz);

    double g[45];
    #pragma unroll
    for (int i = 0; i < 45; ++i) g[i] = 0.0;

    #pragma unroll
    for (int p = 0; p < 5; ++p) {
        const double x = (double)Pgt[(k*5+p)*2 + 0];
        const double y = (double)Pgt[(k*5+p)*2 + 1];
        const double u = (double)qx[p];
        const double v = (double)qz[p];
        const double re[9] = {x, y, 1.0, 0.0, 0.0, 0.0, -x*u, -y*u, -u};
        const double ro[9] = {0.0, 0.0, 0.0, x, y, 1.0, -x*v, -y*v, -v};
        int idx = 0;
        #pragma unroll
        for (int i = 0; i < 9; ++i)
            #pragma unroll
            for (int j = i; j < 9; ++j, ++idx)
                g[idx] += re[i]*re[j] + ro[i]*ro[j];
    }

    #pragma unroll
    for (int off = 32; off > 0; off >>= 1) {
        #pragma unroll
        for (int i = 0; i < 45; ++i) g[i] += __shfl_down(g[i], off);
    }
    if (m == 0) {
        double* dst = gram + (size_t)(combo*BNUM + b) * 45;
        #pragma unroll
        for (int i = 0; i < 45; ++i) dst[i] = g[i];
    }
}

// 192 independent 9x9 symmetric eigen-solves (cyclic Jacobi, double).
__global__ __launch_bounds__(64) void eigen_kernel(
    const double* __restrict__ gram, double* __restrict__ Hout)
{
    const int id = blockIdx.x * 64 + threadIdx.x;
    if (id >= 3*BNUM) return;
    const double* g = gram + (size_t)id * 45;

    double A[81], V[81];
    {
        int idx = 0;
        #pragma unroll 1
        for (int i = 0; i < 9; ++i)
            for (int j = i; j < 9; ++j, ++idx) { A[i*9+j] = g[idx]; A[j*9+i] = g[idx]; }
    }
    // normalize scale (eigenvectors unchanged)
    double gmax = 0.0;
    for (int i = 0; i < 9; ++i) gmax = fmax(gmax, A[i*9+i]);
    const double scl = (gmax > 0.0) ? 1.0/gmax : 1.0;
    for (int i = 0; i < 81; ++i) A[i] *= scl;
    for (int i = 0; i < 81; ++i) V[i] = 0.0;
    for (int i = 0; i < 9; ++i) V[i*9+i] = 1.0;

    #pragma unroll 1
    for (int sweep = 0; sweep < 30; ++sweep) {
        double off = 0.0;
        for (int i = 0; i < 9; ++i)
            for (int j = i+1; j < 9; ++j) off += A[i*9+j]*A[i*9+j];
        if (off < 1e-28) break;
        #pragma unroll 1
        for (int p = 0; p < 8; ++p) {
            #pragma unroll 1
            for (int q = p+1; q < 9; ++q) {
                const double apq = A[p*9+q];
                if (fabs(apq) < 1e-300) continue;
                const double tau = (A[q*9+q] - A[p*9+p]) / (2.0*apq);
                const double t = ((tau >= 0.0) ? 1.0 : -1.0) / (fabs(tau) + sqrt(1.0 + tau*tau));
                const double c = 1.0 / sqrt(1.0 + t*t);
                const double s = t*c;
                #pragma unroll 1
                for (int i = 0; i < 9; ++i) {
                    const double aip = A[i*9+p], aiq = A[i*9+q];
                    A[i*9+p] = c*aip - s*aiq;
                    A[i*9+q] = s*aip + c*aiq;
                }
                #pragma unroll 1
                for (int j = 0; j < 9; ++j) {
                    const double apj = A[p*9+j], aqj = A[q*9+j];
                    A[p*9+j] = c*apj - s*aqj;
                    A[q*9+j] = s*apj + c*aqj;
                }
                #pragma unroll 1
                for (int i = 0; i < 9; ++i) {
                    const double vip = V[i*9+p], viq = V[i*9+q];
                    V[i*9+p] = c*vip - s*viq;
                    V[i*9+q] = s*vip + c*viq;
                }
            }
        }
    }

    int jmin = 0; double dmin = A[0];
    for (int j = 1; j < 9; ++j) { const double d = A[j*9+j]; if (d < dmin) { dmin = d; jmin = j; } }
    double* H = Hout + (size_t)id * 9;
    #pragma unroll 1
    for (int i = 0; i < 9; ++i) H[i] = V[i*9+jmin];
}

// One thread per (k, combo): homography reprojection + masked smooth-L1 sums.
__global__ __launch_bounds__(256) void loss_kernel(
    const float* __restrict__ center, const int* __restrict__ cls_ids,
    const float* __restrict__ ry, const float* __restrict__ size3d,
    const float* __restrict__ Pgt, const float* __restrict__ Qgt,
    const float* __restrict__ off_gt, const float* __restrict__ dep_gt,
    const float* __restrict__ out_off, const float* __restrict__ out_dep,
    const float* __restrict__ calibs, const float* __restrict__ trans_inv,
    const double* __restrict__ Hout, double* __restrict__ partials)
{
    const int combo = blockIdx.y;
    const int k = blockIdx.x * 256 + threadIdx.x;

    float qx[5], qz[5];
    compute_qpred(k, combo, center, cls_ids, ry, size3d,
                  off_gt, dep_gt, out_off, out_dep, calibs, trans_inv, qx, qz);

    const int b = k >> 6;
    const double* H = Hout + (size_t)(combo*BNUM + b) * 9;
    const double h0 = H[0], h1 = H[1], h2 = H[2];
    const double h3 = H[3], h4 = H[4], h5 = H[5];
    const double h6 = H[6], h7 = H[7], h8 = H[8];

    double hs = 0.0, hc = 0.0, rs = 0.0, rc = 0.0;
    #pragma unroll
    for (int p = 0; p < 5; ++p) {
        const double x  = (double)Pgt[(k*5+p)*2 + 0];
        const double y  = (double)Pgt[(k*5+p)*2 + 1];
        const double gx = (double)Qgt[(k*5+p)*3 + 0];
        const double gz = (double)Qgt[(k*5+p)*3 + 2];
        const double nw0 = h0*x + h1*y + h2;
        const double nw1 = h3*x + h4*y + h5;
        const double nw2 = h6*x + h7*y + h8;
        const double den = nw2 + 1e-10;
        const double rx = nw0 / den;
        const double rz = nw1 / den;
        const bool msk = (rx > -40.0) && (rx < 40.0) && (rz > 0.0) && (rz < 80.0);
        if (msk) { hs += sl1(rx, gx) + sl1(rz, gz); hc += 2.0; }
        else     { rs += sl1((double)qx[p], gx) + sl1((double)qz[p], gz); rc += 2.0; }
    }

    #pragma unroll
    for (int off = 32; off > 0; off >>= 1) {
        hs += __shfl_down(hs, off);
        hc += __shfl_down(hc, off);
        rs += __shfl_down(rs, off);
        rc += __shfl_down(rc, off);
    }
    __shared__ double sm[4][4];
    const int wid = threadIdx.x >> 6, lane = threadIdx.x & 63;
    if (lane == 0) { sm[wid][0] = hs; sm[wid][1] = hc; sm[wid][2] = rs; sm[wid][3] = rc; }
    __syncthreads();
    if (threadIdx.x == 0) {
        double a = 0, b2 = 0, c2 = 0, d2 = 0;
        #pragma unroll
        for (int w = 0; w < 4; ++w) { a += sm[w][0]; b2 += sm[w][1]; c2 += sm[w][2]; d2 += sm[w][3]; }
        double* dst = partials + (size_t)(combo*16 + blockIdx.x) * 4;
        dst[0] = a; dst[1] = b2; dst[2] = c2; dst[3] = d2;
    }
}

__global__ void finalize_kernel(const double* __restrict__ partials, float* __restrict__ out)
{
    if (threadIdx.x == 0 && blockIdx.x == 0) {
        double tot = 0.0;
        for (int cmb = 0; cmb < 3; ++cmb) {
            double hs = 0, hc = 0, rs = 0, rc = 0;
            for (int blk = 0; blk < 16; ++blk) {
                const double* p = partials + (size_t)(cmb*16 + blk) * 4;
                hs += p[0]; hc += p[1]; rs += p[2]; rc += p[3];
            }
            tot += hs / fmax(hc, 1.0) + 0.5 * (rs / fmax(rc, 1.0));
        }
        out[0] = (float)(tot / 3.0);
    }
}

extern "C" void kernel_launch(void* const* d_in, const int* in_sizes, int n_in,
                              void* d_out, int out_size, void* d_ws, size_t ws_size,
                              hipStream_t stream)
{
    const float* center  = (const float*)d_in[1];
    const int*   cls     = (const int*)  d_in[2];
    const float* ry      = (const float*)d_in[3];
    const float* size3d  = (const float*)d_in[4];
    const float* Pgt     = (const float*)d_in[5];
    const float* Qgt     = (const float*)d_in[6];
    const float* off_gt  = (const float*)d_in[7];
    const float* dep_gt  = (const float*)d_in[8];
    const float* out_off = (const float*)d_in[9];
    const float* out_dep = (const float*)d_in[10];
    const float* calibs  = (const float*)d_in[11];
    const float* tinv    = (const float*)d_in[12];

    double* gram     = (double*)d_ws;            // 3*64*45 = 8640 doubles
    double* Hout     = gram + 3*64*45;           // 3*64*9  = 1728 doubles
    double* partials = Hout + 3*64*9;            // 3*16*4  = 192 doubles
    float*  out      = (float*)d_out;

    gram_kernel<<<dim3(64,3), 64, 0, stream>>>(center, cls, ry, size3d, Pgt,
        off_gt, dep_gt, out_off, out_dep, calibs, tinv, gram);
    eigen_kernel<<<dim3(3), 64, 0, stream>>>(gram, Hout);
    loss_kernel<<<dim3(16,3), 256, 0, stream>>>(center, cls, ry, size3d, Pgt, Qgt,
        off_gt, dep_gt, out_off, out_dep, calibs, tinv, Hout, partials);
    finalize_kernel<<<1, 64, 0, stream>>>(partials, out);
}

// Round 2
// 186.803 us; speedup vs baseline: 4.6913x; 4.6913x over previous
//
#include <hip/hip_runtime.h>
#include <math.h>

#define KTOT 4096
#define BNUM 64
#define MNUM 64
#define NSWEEP 12

__device__ const float c_cls_mean[3][3] = {
    {1.76255119f, 0.66068622f, 0.84422524f},
    {1.52563191462f, 1.62856739989f, 3.88311640418f},
    {1.73698127f, 0.59706367f, 1.76282397f}
};

// Compute the 5 Qpred (x,z) points for element k under combo c (f32, matches JAX).
__device__ __forceinline__ void compute_qpred(
    int k, int combo,
    const float* __restrict__ center, const int* __restrict__ cls_ids,
    const float* __restrict__ ry, const float* __restrict__ size3d,
    const float* __restrict__ off_gt, const float* __restrict__ dep_gt,
    const float* __restrict__ out_off, const float* __restrict__ out_dep,
    const float* __restrict__ calibs, const float* __restrict__ trans_inv,
    float* qx, float* qz)
{
    const int b = k >> 6;
    const float cx = center[2*k], cy = center[2*k+1];
    const int cid = cls_ids[k];
    const float d1 = size3d[3*k+1] + c_cls_mean[cid][1];
    const float d2 = size3d[3*k+2] + c_cls_mean[cid][2];
    float sn, cs;
    sincosf(ry[k], &sn, &cs);

    const float* C = calibs + b*12;
    const float f  = C[0];
    const float cu = C[2];
    const float tx = C[3];
    const float t_x = -tx / f;

    const float* TI = trans_inv + b*6;
    const float s   = TI[0];
    const float t0x = TI[2];

    float ox, dep;
    if (combo == 0)      { ox = off_gt[2*k];  dep = out_dep[k]; }
    else if (combo == 1) { ox = out_off[2*k]; dep = dep_gt[k]; }
    else                 { ox = out_off[2*k]; dep = out_dep[k]; }

    const float uv4x = (cx + ox) * 4.0f;
    const float projx = s * uv4x + t0x;
    const float px = (projx - cu) * dep / f + t_x;
    const float Px = px;
    const float Pz = dep;

    const float r1t[4] = {0.5f, -0.5f, -0.5f, 0.5f};
    const float r2t[4] = {0.5f,  0.5f, -0.5f, -0.5f};
    qx[0] = Px; qz[0] = Pz;
    #pragma unroll
    for (int n = 0; n < 4; ++n) {
        const float sx = d2 * r2t[n];
        const float sz = d1 * r1t[n];
        qx[n+1] = Px + (cs*sx + sn*sz);
        qz[n+1] = Pz + (-sn*sx + cs*sz);
    }
}

__device__ __forceinline__ double sl1(double p, double t) {
    double d = p - t, ad = fabs(d);
    return ad < 1.0 ? 0.5*d*d : ad - 0.5;
}

// One wave per (batch, combo): accumulate 9x9 Gram, write FULL 81-entry matrix.
__global__ __launch_bounds__(64) void gram_kernel(
    const float* __restrict__ center, const int* __restrict__ cls_ids,
    const float* __restrict__ ry, const float* __restrict__ size3d,
    const float* __restrict__ Pgt,
    const float* __restrict__ off_gt, const float* __restrict__ dep_gt,
    const float* __restrict__ out_off, const float* __restrict__ out_dep,
    const float* __restrict__ calibs, const float* __restrict__ trans_inv,
    double* __restrict__ gram)
{
    const int b = blockIdx.x, combo = blockIdx.y;
    const int m = threadIdx.x;
    const int k = (b << 6) + m;

    float qx[5], qz[5];
    compute_qpred(k, combo, center, cls_ids, ry, size3d,
                  off_gt, dep_gt, out_off, out_dep, calibs, trans_inv, qx, qz);

    double g[45];
    #pragma unroll
    for (int i = 0; i < 45; ++i) g[i] = 0.0;

    #pragma unroll
    for (int p = 0; p < 5; ++p) {
        const double x = (double)Pgt[(k*5+p)*2 + 0];
        const double y = (double)Pgt[(k*5+p)*2 + 1];
        const double u = (double)qx[p];
        const double v = (double)qz[p];
        const double re[9] = {x, y, 1.0, 0.0, 0.0, 0.0, -x*u, -y*u, -u};
        const double ro[9] = {0.0, 0.0, 0.0, x, y, 1.0, -x*v, -y*v, -v};
        int idx = 0;
        #pragma unroll
        for (int i = 0; i < 9; ++i)
            #pragma unroll
            for (int j = i; j < 9; ++j, ++idx)
                g[idx] += re[i]*re[j] + ro[i]*ro[j];
    }

    #pragma unroll
    for (int off = 32; off > 0; off >>= 1) {
        #pragma unroll
        for (int i = 0; i < 45; ++i) g[i] += __shfl_down(g[i], off);
    }
    if (m == 0) {
        double* dst = gram + (size_t)(combo*BNUM + b) * 81;
        int idx = 0;
        #pragma unroll
        for (int i = 0; i < 9; ++i)
            #pragma unroll
            for (int j = i; j < 9; ++j, ++idx) {
                dst[i*9+j] = g[idx];
                if (i != j) dst[j*9+i] = g[idx];
            }
    }
}

// ---- wave-parallel Jacobi: lane r holds row r of A and row r of V ----
template<int P, int Q>
__device__ __forceinline__ void pair_cs(const double a[9], double& c, double& s) {
    const double app = __shfl(a[P], P);   // A[P][P]
    const double apq = __shfl(a[Q], P);   // A[P][Q]
    const double aqq = __shfl(a[Q], Q);   // A[Q][Q]
    if (fabs(apq) > 1e-300) {
        const double tau = (aqq - app) / (2.0 * apq);
        const double t = ((tau >= 0.0) ? 1.0 : -1.0) / (fabs(tau) + sqrt(1.0 + tau*tau));
        c = 1.0 / sqrt(1.0 + t*t);
        s = t * c;
    } else { c = 1.0; s = 0.0; }
}

template<int P0,int Q0,int P1,int Q1,int P2,int Q2,int P3,int Q3>
__device__ __forceinline__ void jacobi_round(double a[9], double v[9], int lane) {
    double c0,s0,c1,s1,c2,s2,c3,s3;
    pair_cs<P0,Q0>(a,c0,s0);
    pair_cs<P1,Q1>(a,c1,s1);
    pair_cs<P2,Q2>(a,c2,s2);
    pair_cs<P3,Q3>(a,c3,s3);

    int partner = lane;
    if      (lane==P0) partner=Q0; else if (lane==Q0) partner=P0;
    else if (lane==P1) partner=Q1; else if (lane==Q1) partner=P1;
    else if (lane==P2) partner=Q2; else if (lane==Q2) partner=P2;
    else if (lane==P3) partner=Q3; else if (lane==Q3) partner=P3;

    double cme = 1.0, sme = 0.0;
    if      (lane==P0||lane==Q0){cme=c0;sme=s0;}
    else if (lane==P1||lane==Q1){cme=c1;sme=s1;}
    else if (lane==P2||lane==Q2){cme=c2;sme=s2;}
    else if (lane==P3||lane==Q3){cme=c3;sme=s3;}
    const bool isp = (lane==P0)||(lane==P1)||(lane==P2)||(lane==P3);
    const bool act = (partner != lane);

    double b[9];
    #pragma unroll
    for (int j = 0; j < 9; ++j) b[j] = __shfl(a[j], partner);
    #pragma unroll
    for (int j = 0; j < 9; ++j) {
        const double rp = cme*a[j] - sme*b[j];   // new row P
        const double rq = sme*b[j] + cme*a[j];   // new row Q (b = row P)
        const double nv = isp ? rp : rq;
        a[j] = act ? nv : a[j];
    }
    // column updates (right-multiply by J), all lanes, disjoint pairs
    { double t=a[P0]; a[P0]=c0*t-s0*a[Q0]; a[Q0]=s0*t+c0*a[Q0]; }
    { double t=a[P1]; a[P1]=c1*t-s1*a[Q1]; a[Q1]=s1*t+c1*a[Q1]; }
    { double t=a[P2]; a[P2]=c2*t-s2*a[Q2]; a[Q2]=s2*t+c2*a[Q2]; }
    { double t=a[P3]; a[P3]=c3*t-s3*a[Q3]; a[Q3]=s3*t+c3*a[Q3]; }
    { double t=v[P0]; v[P0]=c0*t-s0*v[Q0]; v[Q0]=s0*t+c0*v[Q0]; }
    { double t=v[P1]; v[P1]=c1*t-s1*v[Q1]; v[Q1]=s1*t+c1*v[Q1]; }
    { double t=v[P2]; v[P2]=c2*t-s2*v[Q2]; v[Q2]=s2*t+c2*v[Q2]; }
    { double t=v[P3]; v[P3]=c3*t-s3*v[Q3]; v[Q3]=s3*t+c3*v[Q3]; }
}

// One block (one wave) per solve; 192 solves.
__global__ __launch_bounds__(64) void eigen_kernel(
    const double* __restrict__ gram, double* __restrict__ Hout)
{
    const int id = blockIdx.x;
    const int lane = threadIdx.x;
    const double* G = gram + (size_t)id * 81;
    const int row = (lane < 9) ? lane : 0;

    double a[9], v[9];
    #pragma unroll
    for (int j = 0; j < 9; ++j) a[j] = G[row*9 + j];
    #pragma unroll
    for (int j = 0; j < 9; ++j) v[j] = (j == row) ? 1.0 : 0.0;

    #pragma unroll 1
    for (int sweep = 0; sweep < NSWEEP; ++sweep) {
        jacobi_round<1,8,2,7,3,6,4,5>(a,v,lane);
        jacobi_round<0,1,3,8,4,7,5,6>(a,v,lane);
        jacobi_round<0,2,1,3,5,8,6,7>(a,v,lane);
        jacobi_round<0,3,2,4,1,5,7,8>(a,v,lane);
        jacobi_round<0,4,3,5,2,6,1,7>(a,v,lane);
        jacobi_round<0,5,4,6,3,7,2,8>(a,v,lane);
        jacobi_round<0,6,5,7,4,8,1,2>(a,v,lane);
        jacobi_round<0,7,6,8,1,4,2,3>(a,v,lane);
        jacobi_round<0,8,1,6,2,5,3,4>(a,v,lane);
    }

    // my diagonal entry (compile-time selection chain)
    double d = 1e300;
    if      (lane==0) d=a[0]; else if (lane==1) d=a[1]; else if (lane==2) d=a[2];
    else if (lane==3) d=a[3]; else if (lane==4) d=a[4]; else if (lane==5) d=a[5];
    else if (lane==6) d=a[6]; else if (lane==7) d=a[7]; else if (lane==8) d=a[8];
    int idx = lane;
    #pragma unroll
    for (int off = 32; off > 0; off >>= 1) {
        const double od = __shfl_xor(d, off);
        const int    oi = __shfl_xor(idx, off);
        if (od < d || (od == d && oi < idx)) { d = od; idx = oi; }
    }
    const int jmin = idx;
    const double hv =
        (jmin==0)?v[0]:(jmin==1)?v[1]:(jmin==2)?v[2]:(jmin==3)?v[3]:
        (jmin==4)?v[4]:(jmin==5)?v[5]:(jmin==6)?v[6]:(jmin==7)?v[7]:v[8];
    if (lane < 9) Hout[(size_t)id*9 + lane] = hv;
}

// One thread per (k, combo): homography reprojection + masked smooth-L1 sums.
__global__ __launch_bounds__(256) void loss_kernel(
    const float* __restrict__ center, const int* __restrict__ cls_ids,
    const float* __restrict__ ry, const float* __restrict__ size3d,
    const float* __restrict__ Pgt, const float* __restrict__ Qgt,
    const float* __restrict__ off_gt, const float* __restrict__ dep_gt,
    const float* __restrict__ out_off, const float* __restrict__ out_dep,
    const float* __restrict__ calibs, const float* __restrict__ trans_inv,
    const double* __restrict__ Hout, double* __restrict__ partials)
{
    const int combo = blockIdx.y;
    const int k = blockIdx.x * 256 + threadIdx.x;

    float qx[5], qz[5];
    compute_qpred(k, combo, center, cls_ids, ry, size3d,
                  off_gt, dep_gt, out_off, out_dep, calibs, trans_inv, qx, qz);

    const int b = k >> 6;
    const double* H = Hout + (size_t)(combo*BNUM + b) * 9;
    const double h0 = H[0], h1 = H[1], h2 = H[2];
    const double h3 = H[3], h4 = H[4], h5 = H[5];
    const double h6 = H[6], h7 = H[7], h8 = H[8];

    double hs = 0.0, hc = 0.0, rs = 0.0, rc = 0.0;
    #pragma unroll
    for (int p = 0; p < 5; ++p) {
        const double x  = (double)Pgt[(k*5+p)*2 + 0];
        const double y  = (double)Pgt[(k*5+p)*2 + 1];
        const double gx = (double)Qgt[(k*5+p)*3 + 0];
        const double gz = (double)Qgt[(k*5+p)*3 + 2];
        const double nw0 = h0*x + h1*y + h2;
        const double nw1 = h3*x + h4*y + h5;
        const double nw2 = h6*x + h7*y + h8;
        const double den = nw2 + 1e-10;
        const double rx = nw0 / den;
        const double rz = nw1 / den;
        const bool msk = (rx > -40.0) && (rx < 40.0) && (rz > 0.0) && (rz < 80.0);
        if (msk) { hs += sl1(rx, gx) + sl1(rz, gz); hc += 2.0; }
        else     { rs += sl1((double)qx[p], gx) + sl1((double)qz[p], gz); rc += 2.0; }
    }

    #pragma unroll
    for (int off = 32; off > 0; off >>= 1) {
        hs += __shfl_down(hs, off);
        hc += __shfl_down(hc, off);
        rs += __shfl_down(rs, off);
        rc += __shfl_down(rc, off);
    }
    __shared__ double sm[4][4];
    const int wid = threadIdx.x >> 6, lane = threadIdx.x & 63;
    if (lane == 0) { sm[wid][0] = hs; sm[wid][1] = hc; sm[wid][2] = rs; sm[wid][3] = rc; }
    __syncthreads();
    if (threadIdx.x == 0) {
        double a = 0, b2 = 0, c2 = 0, d2 = 0;
        #pragma unroll
        for (int w = 0; w < 4; ++w) { a += sm[w][0]; b2 += sm[w][1]; c2 += sm[w][2]; d2 += sm[w][3]; }
        double* dst = partials + (size_t)(combo*16 + blockIdx.x) * 4;
        dst[0] = a; dst[1] = b2; dst[2] = c2; dst[3] = d2;
    }
}

__global__ void finalize_kernel(const double* __restrict__ partials, float* __restrict__ out)
{
    if (threadIdx.x == 0 && blockIdx.x == 0) {
        double tot = 0.0;
        for (int cmb = 0; cmb < 3; ++cmb) {
            double hs = 0, hc = 0, rs = 0, rc = 0;
            for (int blk = 0; blk < 16; ++blk) {
                const double* p = partials + (size_t)(cmb*16 + blk) * 4;
                hs += p[0]; hc += p[1]; rs += p[2]; rc += p[3];
            }
            tot += hs / fmax(hc, 1.0) + 0.5 * (rs / fmax(rc, 1.0));
        }
        out[0] = (float)(tot / 3.0);
    }
}

extern "C" void kernel_launch(void* const* d_in, const int* in_sizes, int n_in,
                              void* d_out, int out_size, void* d_ws, size_t ws_size,
                              hipStream_t stream)
{
    const float* center  = (const float*)d_in[1];
    const int*   cls     = (const int*)  d_in[2];
    const float* ry      = (const float*)d_in[3];
    const float* size3d  = (const float*)d_in[4];
    const float* Pgt     = (const float*)d_in[5];
    const float* Qgt     = (const float*)d_in[6];
    const float* off_gt  = (const float*)d_in[7];
    const float* dep_gt  = (const float*)d_in[8];
    const float* out_off = (const float*)d_in[9];
    const float* out_dep = (const float*)d_in[10];
    const float* calibs  = (const float*)d_in[11];
    const float* tinv    = (const float*)d_in[12];

    double* gram     = (double*)d_ws;            // 192*81 doubles
    double* Hout     = gram + 192*81;            // 192*9 doubles
    double* partials = Hout + 192*9;             // 3*16*4 doubles
    float*  out      = (float*)d_out;

    gram_kernel<<<dim3(64,3), 64, 0, stream>>>(center, cls, ry, size3d, Pgt,
        off_gt, dep_gt, out_off, out_dep, calibs, tinv, gram);
    eigen_kernel<<<dim3(192), 64, 0, stream>>>(gram, Hout);
    loss_kernel<<<dim3(16,3), 256, 0, stream>>>(center, cls, ry, size3d, Pgt, Qgt,
        off_gt, dep_gt, out_off, out_dep, calibs, tinv, Hout, partials);
    finalize_kernel<<<1, 64, 0, stream>>>(partials, out);
}

// Round 3
// 121.393 us; speedup vs baseline: 7.2190x; 1.5388x over previous
//
#include <hip/hip_runtime.h>
#include <math.h>

#define KTOT 4096
#define BNUM 64
#define MNUM 64
#define NSWEEP 8

__device__ const float c_cls_mean[3][3] = {
    {1.76255119f, 0.66068622f, 0.84422524f},
    {1.52563191462f, 1.62856739989f, 3.88311640418f},
    {1.73698127f, 0.59706367f, 1.76282397f}
};

// Compute the 5 Qpred (x,z) points for element k under combo c (f32, matches JAX).
__device__ __forceinline__ void compute_qpred(
    int k, int combo,
    const float* __restrict__ center, const int* __restrict__ cls_ids,
    const float* __restrict__ ry, const float* __restrict__ size3d,
    const float* __restrict__ off_gt, const float* __restrict__ dep_gt,
    const float* __restrict__ out_off, const float* __restrict__ out_dep,
    const float* __restrict__ calibs, const float* __restrict__ trans_inv,
    float* qx, float* qz)
{
    const int b = k >> 6;
    const float cx = center[2*k];
    const int cid = cls_ids[k];
    const float d1 = size3d[3*k+1] + c_cls_mean[cid][1];
    const float d2 = size3d[3*k+2] + c_cls_mean[cid][2];
    float sn, cs;
    sincosf(ry[k], &sn, &cs);

    const float* C = calibs + b*12;
    const float f  = C[0];
    const float cu = C[2];
    const float tx = C[3];
    const float t_x = -tx / f;

    const float* TI = trans_inv + b*6;
    const float s   = TI[0];
    const float t0x = TI[2];

    float ox, dep;
    if (combo == 0)      { ox = off_gt[2*k];  dep = out_dep[k]; }
    else if (combo == 1) { ox = out_off[2*k]; dep = dep_gt[k]; }
    else                 { ox = out_off[2*k]; dep = out_dep[k]; }

    const float uv4x = (cx + ox) * 4.0f;
    const float projx = s * uv4x + t0x;
    const float px = (projx - cu) * dep / f + t_x;
    const float Px = px;
    const float Pz = dep;

    const float r1t[4] = {0.5f, -0.5f, -0.5f, 0.5f};
    const float r2t[4] = {0.5f,  0.5f, -0.5f, -0.5f};
    qx[0] = Px; qz[0] = Pz;
    #pragma unroll
    for (int n = 0; n < 4; ++n) {
        const float sx = d2 * r2t[n];
        const float sz = d1 * r1t[n];
        qx[n+1] = Px + (cs*sx + sn*sz);
        qz[n+1] = Pz + (-sn*sx + cs*sz);
    }
}

__device__ __forceinline__ double sl1(double p, double t) {
    double d = p - t, ad = fabs(d);
    return ad < 1.0 ? 0.5*d*d : ad - 0.5;
}

// One wave per (batch, combo): accumulate 9x9 Gram, write FULL 81-entry matrix.
__global__ __launch_bounds__(64) void gram_kernel(
    const float* __restrict__ center, const int* __restrict__ cls_ids,
    const float* __restrict__ ry, const float* __restrict__ size3d,
    const float* __restrict__ Pgt,
    const float* __restrict__ off_gt, const float* __restrict__ dep_gt,
    const float* __restrict__ out_off, const float* __restrict__ out_dep,
    const float* __restrict__ calibs, const float* __restrict__ trans_inv,
    double* __restrict__ gram)
{
    const int b = blockIdx.x, combo = blockIdx.y;
    const int m = threadIdx.x;
    const int k = (b << 6) + m;

    float qx[5], qz[5];
    compute_qpred(k, combo, center, cls_ids, ry, size3d,
                  off_gt, dep_gt, out_off, out_dep, calibs, trans_inv, qx, qz);

    double g[45];
    #pragma unroll
    for (int i = 0; i < 45; ++i) g[i] = 0.0;

    #pragma unroll
    for (int p = 0; p < 5; ++p) {
        const double x = (double)Pgt[(k*5+p)*2 + 0];
        const double y = (double)Pgt[(k*5+p)*2 + 1];
        const double u = (double)qx[p];
        const double v = (double)qz[p];
        const double re[9] = {x, y, 1.0, 0.0, 0.0, 0.0, -x*u, -y*u, -u};
        const double ro[9] = {0.0, 0.0, 0.0, x, y, 1.0, -x*v, -y*v, -v};
        int idx = 0;
        #pragma unroll
        for (int i = 0; i < 9; ++i)
            #pragma unroll
            for (int j = i; j < 9; ++j, ++idx)
                g[idx] += re[i]*re[j] + ro[i]*ro[j];
    }

    #pragma unroll
    for (int off = 32; off > 0; off >>= 1) {
        #pragma unroll
        for (int i = 0; i < 45; ++i) g[i] += __shfl_down(g[i], off);
    }
    if (m == 0) {
        double* dst = gram + (size_t)(combo*BNUM + b) * 81;
        int idx = 0;
        #pragma unroll
        for (int i = 0; i < 9; ++i)
            #pragma unroll
            for (int j = i; j < 9; ++j, ++idx) {
                dst[i*9+j] = g[idx];
                if (i != j) dst[j*9+i] = g[idx];
            }
    }
}

// ---- wave-parallel Jacobi: lane r holds row r of A and row r of V ----
// Single rotation-parameter chain per round: each pair's P-lane computes
// (c,s) locally (one masked block -> div/sqrt sequence appears ONCE in the
// instruction stream), then 4 broadcasts deliver them to all lanes.
template<int P0,int Q0,int P1,int Q1,int P2,int Q2,int P3,int Q3>
__device__ __forceinline__ void jacobi_round(double a[9], double v[9], int lane) {
    const bool isP = (lane==P0)||(lane==P1)||(lane==P2)||(lane==P3);
    const bool isQ = (lane==Q0)||(lane==Q1)||(lane==Q2)||(lane==Q3);
    const bool act = isP || isQ;
    const int partner =
        (lane==P0)?Q0:(lane==Q0)?P0:
        (lane==P1)?Q1:(lane==Q1)?P1:
        (lane==P2)?Q2:(lane==Q2)?P2:
        (lane==P3)?Q3:(lane==Q3)?P3: lane;

    // my diagonal A[lane][lane] (compile-time indexed select chain)
    const double mydiag =
        (lane==0)?a[0]:(lane==1)?a[1]:(lane==2)?a[2]:(lane==3)?a[3]:
        (lane==4)?a[4]:(lane==5)?a[5]:(lane==6)?a[6]:(lane==7)?a[7]:a[8];
    // my off-diagonal A[lane][partner]
    const double offd =
        (lane==P0)?a[Q0]:(lane==Q0)?a[P0]:
        (lane==P1)?a[Q1]:(lane==Q1)?a[P1]:
        (lane==P2)?a[Q2]:(lane==Q2)?a[P2]:
        (lane==P3)?a[Q3]:(lane==Q3)?a[P3]: 0.0;

    const double pdiag = __shfl(mydiag, partner);

    // Only P-lanes compute the rotation (app=mydiag, aqq=pdiag, apq=offd).
    double cl = 1.0, sl_ = 0.0;
    if (isP && fabs(offd) > 1e-300) {
        const double tau = (pdiag - mydiag) / (2.0 * offd);
        const double t = ((tau >= 0.0) ? 1.0 : -1.0) / (fabs(tau) + sqrt(1.0 + tau*tau));
        cl = 1.0 / sqrt(1.0 + t*t);
        sl_ = t * cl;
    }
    const double c0 = __shfl(cl, P0), s0 = __shfl(sl_, P0);
    const double c1 = __shfl(cl, P1), s1 = __shfl(sl_, P1);
    const double c2 = __shfl(cl, P2), s2 = __shfl(sl_, P2);
    const double c3 = __shfl(cl, P3), s3 = __shfl(sl_, P3);

    const double cme = (lane==P0||lane==Q0)?c0:(lane==P1||lane==Q1)?c1:
                       (lane==P2||lane==Q2)?c2:(lane==P3||lane==Q3)?c3:1.0;
    const double sme = (lane==P0||lane==Q0)?s0:(lane==P1||lane==Q1)?s1:
                       (lane==P2||lane==Q2)?s2:(lane==P3||lane==Q3)?s3:0.0;

    // row exchange + row update (left multiply)
    double b[9];
    #pragma unroll
    for (int j = 0; j < 9; ++j) b[j] = __shfl(a[j], partner);
    #pragma unroll
    for (int j = 0; j < 9; ++j) {
        const double rp = cme*a[j] - sme*b[j];   // new row P (b = row Q)
        const double rq = sme*b[j] + cme*a[j];   // new row Q (b = row P)
        const double nv = isP ? rp : rq;
        a[j] = act ? nv : a[j];
    }
    // column updates (right multiply), disjoint pairs, all lanes
    { double t=a[P0]; a[P0]=c0*t-s0*a[Q0]; a[Q0]=s0*t+c0*a[Q0]; }
    { double t=a[P1]; a[P1]=c1*t-s1*a[Q1]; a[Q1]=s1*t+c1*a[Q1]; }
    { double t=a[P2]; a[P2]=c2*t-s2*a[Q2]; a[Q2]=s2*t+c2*a[Q2]; }
    { double t=a[P3]; a[P3]=c3*t-s3*a[Q3]; a[Q3]=s3*t+c3*a[Q3]; }
    { double t=v[P0]; v[P0]=c0*t-s0*v[Q0]; v[Q0]=s0*t+c0*v[Q0]; }
    { double t=v[P1]; v[P1]=c1*t-s1*v[Q1]; v[Q1]=s1*t+c1*v[Q1]; }
    { double t=v[P2]; v[P2]=c2*t-s2*v[Q2]; v[Q2]=s2*t+c2*v[Q2]; }
    { double t=v[P3]; v[P3]=c3*t-s3*v[Q3]; v[Q3]=s3*t+c3*v[Q3]; }
}

// One block (one wave) per solve; 192 solves.
__global__ __launch_bounds__(64) void eigen_kernel(
    const double* __restrict__ gram, double* __restrict__ Hout)
{
    const int id = blockIdx.x;
    const int lane = threadIdx.x;
    const double* G = gram + (size_t)id * 81;
    const int row = (lane < 9) ? lane : 0;

    double a[9], v[9];
    #pragma unroll
    for (int j = 0; j < 9; ++j) a[j] = G[row*9 + j];
    #pragma unroll
    for (int j = 0; j < 9; ++j) v[j] = (j == row) ? 1.0 : 0.0;

    #pragma unroll 1
    for (int sweep = 0; sweep < NSWEEP; ++sweep) {
        jacobi_round<1,8,2,7,3,6,4,5>(a,v,lane);
        jacobi_round<0,1,3,8,4,7,5,6>(a,v,lane);
        jacobi_round<0,2,1,3,5,8,6,7>(a,v,lane);
        jacobi_round<0,3,2,4,1,5,7,8>(a,v,lane);
        jacobi_round<0,4,3,5,2,6,1,7>(a,v,lane);
        jacobi_round<0,5,4,6,3,7,2,8>(a,v,lane);
        jacobi_round<0,6,5,7,4,8,1,2>(a,v,lane);
        jacobi_round<0,7,6,8,1,4,2,3>(a,v,lane);
        jacobi_round<0,8,1,6,2,5,3,4>(a,v,lane);
    }

    // my diagonal entry
    double d = 1e300;
    if      (lane==0) d=a[0]; else if (lane==1) d=a[1]; else if (lane==2) d=a[2];
    else if (lane==3) d=a[3]; else if (lane==4) d=a[4]; else if (lane==5) d=a[5];
    else if (lane==6) d=a[6]; else if (lane==7) d=a[7]; else if (lane==8) d=a[8];
    int idx = lane;
    #pragma unroll
    for (int off = 32; off > 0; off >>= 1) {
        const double od = __shfl_xor(d, off);
        const int    oi = __shfl_xor(idx, off);
        if (od < d || (od == d && oi < idx)) { d = od; idx = oi; }
    }
    const int jmin = idx;
    const double hv =
        (jmin==0)?v[0]:(jmin==1)?v[1]:(jmin==2)?v[2]:(jmin==3)?v[3]:
        (jmin==4)?v[4]:(jmin==5)?v[5]:(jmin==6)?v[6]:(jmin==7)?v[7]:v[8];
    if (lane < 9) Hout[(size_t)id*9 + lane] = hv;
}

// One thread per (k, combo): homography reprojection + masked smooth-L1 sums.
__global__ __launch_bounds__(256) void loss_kernel(
    const float* __restrict__ center, const int* __restrict__ cls_ids,
    const float* __restrict__ ry, const float* __restrict__ size3d,
    const float* __restrict__ Pgt, const float* __restrict__ Qgt,
    const float* __restrict__ off_gt, const float* __restrict__ dep_gt,
    const float* __restrict__ out_off, const float* __restrict__ out_dep,
    const float* __restrict__ calibs, const float* __restrict__ trans_inv,
    const double* __restrict__ Hout, double* __restrict__ partials)
{
    const int combo = blockIdx.y;
    const int k = blockIdx.x * 256 + threadIdx.x;

    float qx[5], qz[5];
    compute_qpred(k, combo, center, cls_ids, ry, size3d,
                  off_gt, dep_gt, out_off, out_dep, calibs, trans_inv, qx, qz);

    const int b = k >> 6;
    const double* H = Hout + (size_t)(combo*BNUM + b) * 9;
    const double h0 = H[0], h1 = H[1], h2 = H[2];
    const double h3 = H[3], h4 = H[4], h5 = H[5];
    const double h6 = H[6], h7 = H[7], h8 = H[8];

    double hs = 0.0, hc = 0.0, rs = 0.0, rc = 0.0;
    #pragma unroll
    for (int p = 0; p < 5; ++p) {
        const double x  = (double)Pgt[(k*5+p)*2 + 0];
        const double y  = (double)Pgt[(k*5+p)*2 + 1];
        const double gx = (double)Qgt[(k*5+p)*3 + 0];
        const double gz = (double)Qgt[(k*5+p)*3 + 2];
        const double nw0 = h0*x + h1*y + h2;
        const double nw1 = h3*x + h4*y + h5;
        const double nw2 = h6*x + h7*y + h8;
        const double den = nw2 + 1e-10;
        const double rx = nw0 / den;
        const double rz = nw1 / den;
        const bool msk = (rx > -40.0) && (rx < 40.0) && (rz > 0.0) && (rz < 80.0);
        if (msk) { hs += sl1(rx, gx) + sl1(rz, gz); hc += 2.0; }
        else     { rs += sl1((double)qx[p], gx) + sl1((double)qz[p], gz); rc += 2.0; }
    }

    #pragma unroll
    for (int off = 32; off > 0; off >>= 1) {
        hs += __shfl_down(hs, off);
        hc += __shfl_down(hc, off);
        rs += __shfl_down(rs, off);
        rc += __shfl_down(rc, off);
    }
    __shared__ double sm[4][4];
    const int wid = threadIdx.x >> 6, lane = threadIdx.x & 63;
    if (lane == 0) { sm[wid][0] = hs; sm[wid][1] = hc; sm[wid][2] = rs; sm[wid][3] = rc; }
    __syncthreads();
    if (threadIdx.x == 0) {
        double a = 0, b2 = 0, c2 = 0, d2 = 0;
        #pragma unroll
        for (int w = 0; w < 4; ++w) { a += sm[w][0]; b2 += sm[w][1]; c2 += sm[w][2]; d2 += sm[w][3]; }
        double* dst = partials + (size_t)(combo*16 + blockIdx.x) * 4;
        dst[0] = a; dst[1] = b2; dst[2] = c2; dst[3] = d2;
    }
}

__global__ void finalize_kernel(const double* __restrict__ partials, float* __restrict__ out)
{
    if (threadIdx.x == 0 && blockIdx.x == 0) {
        double tot = 0.0;
        for (int cmb = 0; cmb < 3; ++cmb) {
            double hs = 0, hc = 0, rs = 0, rc = 0;
            for (int blk = 0; blk < 16; ++blk) {
                const double* p = partials + (size_t)(cmb*16 + blk) * 4;
                hs += p[0]; hc += p[1]; rs += p[2]; rc += p[3];
            }
            tot += hs / fmax(hc, 1.0) + 0.5 * (rs / fmax(rc, 1.0));
        }
        out[0] = (float)(tot / 3.0);
    }
}

extern "C" void kernel_launch(void* const* d_in, const int* in_sizes, int n_in,
                              void* d_out, int out_size, void* d_ws, size_t ws_size,
                              hipStream_t stream)
{
    const float* center  = (const float*)d_in[1];
    const int*   cls     = (const int*)  d_in[2];
    const float* ry      = (const float*)d_in[3];
    const float* size3d  = (const float*)d_in[4];
    const float* Pgt     = (const float*)d_in[5];
    const float* Qgt     = (const float*)d_in[6];
    const float* off_gt  = (const float*)d_in[7];
    const float* dep_gt  = (const float*)d_in[8];
    const float* out_off = (const float*)d_in[9];
    const float* out_dep = (const float*)d_in[10];
    const float* calibs  = (const float*)d_in[11];
    const float* tinv    = (const float*)d_in[12];

    double* gram     = (double*)d_ws;            // 192*81 doubles
    double* Hout     = gram + 192*81;            // 192*9 doubles
    double* partials = Hout + 192*9;             // 3*16*4 doubles
    float*  out      = (float*)d_out;

    gram_kernel<<<dim3(64,3), 64, 0, stream>>>(center, cls, ry, size3d, Pgt,
        off_gt, dep_gt, out_off, out_dep, calibs, tinv, gram);
    eigen_kernel<<<dim3(192), 64, 0, stream>>>(gram, Hout);
    loss_kernel<<<dim3(16,3), 256, 0, stream>>>(center, cls, ry, size3d, Pgt, Qgt,
        off_gt, dep_gt, out_off, out_dep, calibs, tinv, Hout, partials);
    finalize_kernel<<<1, 64, 0, stream>>>(partials, out);
}

// Round 4
// 25.336 us; speedup vs baseline: 34.5892x; 4.7914x over previous
//
#include <hip/hip_runtime.h>
#include <math.h>

#define KTOT 4096
#define BNUM 64
#define MNUM 64
#define NITER 16

// packed upper-tri index (i<=j), row-major by i: row i starts at 9i - i(i-1)/2
#define UIDX(i,j) ((i)*9 - (i)*((i)-1)/2 + ((j)-(i)))
// packed lower-tri index (j<=i)
#define LIDX(i,j) ((i)*((i)+1)/2 + (j))

__device__ const float c_cls_mean[3][3] = {
    {1.76255119f, 0.66068622f, 0.84422524f},
    {1.52563191462f, 1.62856739989f, 3.88311640418f},
    {1.73698127f, 0.59706367f, 1.76282397f}
};

// Compute the 5 Qpred (x,z) points for element k under combo c (f32, matches JAX).
__device__ __forceinline__ void compute_qpred(
    int k, int combo,
    const float* __restrict__ center, const int* __restrict__ cls_ids,
    const float* __restrict__ ry, const float* __restrict__ size3d,
    const float* __restrict__ off_gt, const float* __restrict__ dep_gt,
    const float* __restrict__ out_off, const float* __restrict__ out_dep,
    const float* __restrict__ calibs, const float* __restrict__ trans_inv,
    float* qx, float* qz)
{
    const int b = k >> 6;
    const float cx = center[2*k];
    const int cid = cls_ids[k];
    const float d1 = size3d[3*k+1] + c_cls_mean[cid][1];
    const float d2 = size3d[3*k+2] + c_cls_mean[cid][2];
    float sn, cs;
    sincosf(ry[k], &sn, &cs);

    const float* C = calibs + b*12;
    const float f  = C[0];
    const float cu = C[2];
    const float tx = C[3];
    const float t_x = -tx / f;

    const float* TI = trans_inv + b*6;
    const float s   = TI[0];
    const float t0x = TI[2];

    float ox, dep;
    if (combo == 0)      { ox = off_gt[2*k];  dep = out_dep[k]; }
    else if (combo == 1) { ox = out_off[2*k]; dep = dep_gt[k]; }
    else                 { ox = out_off[2*k]; dep = out_dep[k]; }

    const float uv4x = (cx + ox) * 4.0f;
    const float projx = s * uv4x + t0x;
    const float px = (projx - cu) * dep / f + t_x;
    const float Px = px;
    const float Pz = dep;

    const float r1t[4] = {0.5f, -0.5f, -0.5f, 0.5f};
    const float r2t[4] = {0.5f,  0.5f, -0.5f, -0.5f};
    qx[0] = Px; qz[0] = Pz;
    #pragma unroll
    for (int n = 0; n < 4; ++n) {
        const float sx = d2 * r2t[n];
        const float sz = d1 * r1t[n];
        qx[n+1] = Px + (cs*sx + sn*sz);
        qz[n+1] = Pz + (-sn*sx + cs*sz);
    }
}

__device__ __forceinline__ double sl1(double p, double t) {
    double d = p - t, ad = fabs(d);
    return ad < 1.0 ? 0.5*d*d : ad - 0.5;
}

// One wave per (batch, combo): accumulate 9x9 Gram, write packed 45-entry upper tri.
__global__ __launch_bounds__(64) void gram_kernel(
    const float* __restrict__ center, const int* __restrict__ cls_ids,
    const float* __restrict__ ry, const float* __restrict__ size3d,
    const float* __restrict__ Pgt,
    const float* __restrict__ off_gt, const float* __restrict__ dep_gt,
    const float* __restrict__ out_off, const float* __restrict__ out_dep,
    const float* __restrict__ calibs, const float* __restrict__ trans_inv,
    double* __restrict__ gram)
{
    const int b = blockIdx.x, combo = blockIdx.y;
    const int m = threadIdx.x;
    const int k = (b << 6) + m;

    float qx[5], qz[5];
    compute_qpred(k, combo, center, cls_ids, ry, size3d,
                  off_gt, dep_gt, out_off, out_dep, calibs, trans_inv, qx, qz);

    double g[45];
    #pragma unroll
    for (int i = 0; i < 45; ++i) g[i] = 0.0;

    #pragma unroll
    for (int p = 0; p < 5; ++p) {
        const double x = (double)Pgt[(k*5+p)*2 + 0];
        const double y = (double)Pgt[(k*5+p)*2 + 1];
        const double u = (double)qx[p];
        const double v = (double)qz[p];
        const double re[9] = {x, y, 1.0, 0.0, 0.0, 0.0, -x*u, -y*u, -u};
        const double ro[9] = {0.0, 0.0, 0.0, x, y, 1.0, -x*v, -y*v, -v};
        int idx = 0;
        #pragma unroll
        for (int i = 0; i < 9; ++i)
            #pragma unroll
            for (int j = i; j < 9; ++j, ++idx)
                g[idx] += re[i]*re[j] + ro[i]*ro[j];
    }

    #pragma unroll
    for (int off = 32; off > 0; off >>= 1) {
        #pragma unroll
        for (int i = 0; i < 45; ++i) g[i] += __shfl_down(g[i], off);
    }
    if (m == 0) {
        double* dst = gram + (size_t)(combo*BNUM + b) * 45;
        #pragma unroll
        for (int i = 0; i < 45; ++i) dst[i] = g[i];
    }
}

// Per-lane smallest-eigenvector solve: Cholesky of G+eps*I (same eigenvectors)
// + fixed inverse-iteration. 192 independent lanes, no cross-lane traffic,
// fully register-resident (all indices compile-time).
__global__ __launch_bounds__(64, 1) void eigen_kernel(
    const double* __restrict__ gram, double* __restrict__ Hout)
{
    const int id = blockIdx.x * 64 + threadIdx.x;
    const double* G = gram + (size_t)id * 45;

    double Gm[45];
    #pragma unroll
    for (int i = 0; i < 45; ++i) Gm[i] = G[i];

    double gmax = 0.0;
    #pragma unroll
    for (int i = 0; i < 9; ++i) gmax = fmax(gmax, Gm[UIDX(i,i)]);
    const double ridge = 1e-10 * gmax;
    #pragma unroll
    for (int i = 0; i < 9; ++i) Gm[UIDX(i,i)] += ridge;

    // Cholesky: M = L L^T, L lower-tri packed, linv = 1/diag(L)
    double L[45], linv[9];
    #pragma unroll
    for (int i = 0; i < 9; ++i) {
        #pragma unroll
        for (int j = 0; j <= i; ++j) {
            double s = Gm[UIDX(j,i)];
            #pragma unroll
            for (int t = 0; t < j; ++t) s -= L[LIDX(i,t)] * L[LIDX(j,t)];
            if (j < i) {
                L[LIDX(i,j)] = s * linv[j];
            } else {
                const double d = fmax(s, ridge * 1e-2);  // pivot guard
                const double r = sqrt(d);
                L[LIDX(i,i)] = r;
                linv[i] = 1.0 / r;
            }
        }
    }

    // inverse iteration: x <- normalize( (L L^T)^{-1} x )
    double x[9];
    #pragma unroll
    for (int j = 0; j < 9; ++j) x[j] = 1.0 + 0.0625 * j;

    #pragma unroll 1
    for (int it = 0; it < NITER; ++it) {
        double y[9];
        #pragma unroll
        for (int i = 0; i < 9; ++i) {
            double s = x[i];
            #pragma unroll
            for (int t = 0; t < i; ++t) s -= L[LIDX(i,t)] * y[t];
            y[i] = s * linv[i];
        }
        double z[9];
        #pragma unroll
        for (int ii = 8; ii >= 0; --ii) {
            double s = y[ii];
            #pragma unroll
            for (int t = 8; t > 0; --t)
                if (t > ii) s -= L[LIDX(t,ii)] * z[t];
            z[ii] = s * linv[ii];
        }
        double n = 0.0;
        #pragma unroll
        for (int j = 0; j < 9; ++j) n += z[j]*z[j];
        const double inv = 1.0 / sqrt(n);
        #pragma unroll
        for (int j = 0; j < 9; ++j) x[j] = z[j] * inv;
    }

    double* H = Hout + (size_t)id * 9;
    #pragma unroll
    for (int j = 0; j < 9; ++j) H[j] = x[j];
}

// One thread per (k, combo): homography reprojection + masked smooth-L1 sums.
__global__ __launch_bounds__(256) void loss_kernel(
    const float* __restrict__ center, const int* __restrict__ cls_ids,
    const float* __restrict__ ry, const float* __restrict__ size3d,
    const float* __restrict__ Pgt, const float* __restrict__ Qgt,
    const float* __restrict__ off_gt, const float* __restrict__ dep_gt,
    const float* __restrict__ out_off, const float* __restrict__ out_dep,
    const float* __restrict__ calibs, const float* __restrict__ trans_inv,
    const double* __restrict__ Hout, double* __restrict__ partials)
{
    const int combo = blockIdx.y;
    const int k = blockIdx.x * 256 + threadIdx.x;

    float qx[5], qz[5];
    compute_qpred(k, combo, center, cls_ids, ry, size3d,
                  off_gt, dep_gt, out_off, out_dep, calibs, trans_inv, qx, qz);

    const int b = k >> 6;
    const double* H = Hout + (size_t)(combo*BNUM + b) * 9;
    const double h0 = H[0], h1 = H[1], h2 = H[2];
    const double h3 = H[3], h4 = H[4], h5 = H[5];
    const double h6 = H[6], h7 = H[7], h8 = H[8];

    double hs = 0.0, hc = 0.0, rs = 0.0, rc = 0.0;
    #pragma unroll
    for (int p = 0; p < 5; ++p) {
        const double x  = (double)Pgt[(k*5+p)*2 + 0];
        const double y  = (double)Pgt[(k*5+p)*2 + 1];
        const double gx = (double)Qgt[(k*5+p)*3 + 0];
        const double gz = (double)Qgt[(k*5+p)*3 + 2];
        const double nw0 = h0*x + h1*y + h2;
        const double nw1 = h3*x + h4*y + h5;
        const double nw2 = h6*x + h7*y + h8;
        const double den = nw2 + 1e-10;
        const double rx = nw0 / den;
        const double rz = nw1 / den;
        const bool msk = (rx > -40.0) && (rx < 40.0) && (rz > 0.0) && (rz < 80.0);
        if (msk) { hs += sl1(rx, gx) + sl1(rz, gz); hc += 2.0; }
        else     { rs += sl1((double)qx[p], gx) + sl1((double)qz[p], gz); rc += 2.0; }
    }

    #pragma unroll
    for (int off = 32; off > 0; off >>= 1) {
        hs += __shfl_down(hs, off);
        hc += __shfl_down(hc, off);
        rs += __shfl_down(rs, off);
        rc += __shfl_down(rc, off);
    }
    __shared__ double sm[4][4];
    const int wid = threadIdx.x >> 6, lane = threadIdx.x & 63;
    if (lane == 0) { sm[wid][0] = hs; sm[wid][1] = hc; sm[wid][2] = rs; sm[wid][3] = rc; }
    __syncthreads();
    if (threadIdx.x == 0) {
        double a = 0, b2 = 0, c2 = 0, d2 = 0;
        #pragma unroll
        for (int w = 0; w < 4; ++w) { a += sm[w][0]; b2 += sm[w][1]; c2 += sm[w][2]; d2 += sm[w][3]; }
        double* dst = partials + (size_t)(combo*16 + blockIdx.x) * 4;
        dst[0] = a; dst[1] = b2; dst[2] = c2; dst[3] = d2;
    }
}

__global__ void finalize_kernel(const double* __restrict__ partials, float* __restrict__ out)
{
    if (threadIdx.x == 0 && blockIdx.x == 0) {
        double tot = 0.0;
        for (int cmb = 0; cmb < 3; ++cmb) {
            double hs = 0, hc = 0, rs = 0, rc = 0;
            for (int blk = 0; blk < 16; ++blk) {
                const double* p = partials + (size_t)(cmb*16 + blk) * 4;
                hs += p[0]; hc += p[1]; rs += p[2]; rc += p[3];
            }
            tot += hs / fmax(hc, 1.0) + 0.5 * (rs / fmax(rc, 1.0));
        }
        out[0] = (float)(tot / 3.0);
    }
}

extern "C" void kernel_launch(void* const* d_in, const int* in_sizes, int n_in,
                              void* d_out, int out_size, void* d_ws, size_t ws_size,
                              hipStream_t stream)
{
    const float* center  = (const float*)d_in[1];
    const int*   cls     = (const int*)  d_in[2];
    const float* ry      = (const float*)d_in[3];
    const float* size3d  = (const float*)d_in[4];
    const float* Pgt     = (const float*)d_in[5];
    const float* Qgt     = (const float*)d_in[6];
    const float* off_gt  = (const float*)d_in[7];
    const float* dep_gt  = (const float*)d_in[8];
    const float* out_off = (const float*)d_in[9];
    const float* out_dep = (const float*)d_in[10];
    const float* calibs  = (const float*)d_in[11];
    const float* tinv    = (const float*)d_in[12];

    double* gram     = (double*)d_ws;            // 192*45 doubles
    double* Hout     = gram + 192*45;            // 192*9 doubles
    double* partials = Hout + 192*9;             // 3*16*4 doubles
    float*  out      = (float*)d_out;

    gram_kernel<<<dim3(64,3), 64, 0, stream>>>(center, cls, ry, size3d, Pgt,
        off_gt, dep_gt, out_off, out_dep, calibs, tinv, gram);
    eigen_kernel<<<dim3(3), 64, 0, stream>>>(gram, Hout);
    loss_kernel<<<dim3(16,3), 256, 0, stream>>>(center, cls, ry, size3d, Pgt, Qgt,
        off_gt, dep_gt, out_off, out_dep, calibs, tinv, Hout, partials);
    finalize_kernel<<<1, 64, 0, stream>>>(partials, out);
}

// Round 5
// 19.062 us; speedup vs baseline: 45.9734x; 1.3291x over previous
//
#include <hip/hip_runtime.h>
#include <math.h>

#define KTOT 4096
#define BNUM 64
#define MNUM 64
#define NITER 16

// packed upper-tri index (i<=j), row-major by i
#define UIDX(i,j) ((i)*9 - (i)*((i)-1)/2 + ((j)-(i)))
// packed lower-tri index (j<=i)
#define LIDX(i,j) ((i)*((i)+1)/2 + (j))

__device__ const float c_cls_mean[3][3] = {
    {1.76255119f, 0.66068622f, 0.84422524f},
    {1.52563191462f, 1.62856739989f, 3.88311640418f},
    {1.73698127f, 0.59706367f, 1.76282397f}
};

// Compute the 5 Qpred (x,z) points for element k under combo c (f32, matches JAX).
__device__ __forceinline__ void compute_qpred(
    int k, int combo,
    const float* __restrict__ center, const int* __restrict__ cls_ids,
    const float* __restrict__ ry, const float* __restrict__ size3d,
    const float* __restrict__ off_gt, const float* __restrict__ dep_gt,
    const float* __restrict__ out_off, const float* __restrict__ out_dep,
    const float* __restrict__ calibs, const float* __restrict__ trans_inv,
    float* qx, float* qz)
{
    const int b = k >> 6;
    const float cx = center[2*k];
    const int cid = cls_ids[k];
    const float d1 = size3d[3*k+1] + c_cls_mean[cid][1];
    const float d2 = size3d[3*k+2] + c_cls_mean[cid][2];
    float sn, cs;
    sincosf(ry[k], &sn, &cs);

    const float* C = calibs + b*12;
    const float f  = C[0];
    const float cu = C[2];
    const float tx = C[3];
    const float t_x = -tx / f;

    const float* TI = trans_inv + b*6;
    const float s   = TI[0];
    const float t0x = TI[2];

    float ox, dep;
    if (combo == 0)      { ox = off_gt[2*k];  dep = out_dep[k]; }
    else if (combo == 1) { ox = out_off[2*k]; dep = dep_gt[k]; }
    else                 { ox = out_off[2*k]; dep = out_dep[k]; }

    const float uv4x = (cx + ox) * 4.0f;
    const float projx = s * uv4x + t0x;
    const float px = (projx - cu) * dep / f + t_x;
    const float Px = px;
    const float Pz = dep;

    const float r1t[4] = {0.5f, -0.5f, -0.5f, 0.5f};
    const float r2t[4] = {0.5f,  0.5f, -0.5f, -0.5f};
    qx[0] = Px; qz[0] = Pz;
    #pragma unroll
    for (int n = 0; n < 4; ++n) {
        const float sx = d2 * r2t[n];
        const float sz = d1 * r1t[n];
        qx[n+1] = Px + (cs*sx + sn*sz);
        qz[n+1] = Pz + (-sn*sx + cs*sz);
    }
}

__device__ __forceinline__ double sl1(double p, double t) {
    double d = p - t, ad = fabs(d);
    return ad < 1.0 ? 0.5*d*d : ad - 0.5;
}

// One block = one (batch, combo): Gram -> Cholesky+inverse-iteration (all lanes
// redundant, register-resident) -> per-lane masked loss -> one partial write.
__global__ __launch_bounds__(64, 1) void fused_kernel(
    const float* __restrict__ center, const int* __restrict__ cls_ids,
    const float* __restrict__ ry, const float* __restrict__ size3d,
    const float* __restrict__ Pgt, const float* __restrict__ Qgt,
    const float* __restrict__ off_gt, const float* __restrict__ dep_gt,
    const float* __restrict__ out_off, const float* __restrict__ out_dep,
    const float* __restrict__ calibs, const float* __restrict__ trans_inv,
    double* __restrict__ partials)
{
    const int b = blockIdx.x, combo = blockIdx.y;
    const int m = threadIdx.x;
    const int k = (b << 6) + m;

    float qx[5], qz[5];
    compute_qpred(k, combo, center, cls_ids, ry, size3d,
                  off_gt, dep_gt, out_off, out_dep, calibs, trans_inv, qx, qz);

    // ---- Gram accumulation (per-lane) ----
    double g[45];
    #pragma unroll
    for (int i = 0; i < 45; ++i) g[i] = 0.0;

    double Px[5], Py[5];   // keep Pgt in registers for the loss phase
    #pragma unroll
    for (int p = 0; p < 5; ++p) {
        const double x = (double)Pgt[(k*5+p)*2 + 0];
        const double y = (double)Pgt[(k*5+p)*2 + 1];
        Px[p] = x; Py[p] = y;
        const double u = (double)qx[p];
        const double v = (double)qz[p];
        const double re[9] = {x, y, 1.0, 0.0, 0.0, 0.0, -x*u, -y*u, -u};
        const double ro[9] = {0.0, 0.0, 0.0, x, y, 1.0, -x*v, -y*v, -v};
        int idx = 0;
        #pragma unroll
        for (int i = 0; i < 9; ++i)
            #pragma unroll
            for (int j = i; j < 9; ++j, ++idx)
                g[idx] += re[i]*re[j] + ro[i]*ro[j];
    }

    // ---- butterfly reduce: ALL lanes end with the full Gram ----
    #pragma unroll
    for (int off = 32; off > 0; off >>= 1) {
        #pragma unroll
        for (int i = 0; i < 45; ++i) g[i] += __shfl_xor(g[i], off);
    }

    // ---- ridge shift (eigenvectors unchanged) ----
    double gmax = 0.0;
    #pragma unroll
    for (int i = 0; i < 9; ++i) gmax = fmax(gmax, g[UIDX(i,i)]);
    const double ridge = 1e-10 * gmax;
    #pragma unroll
    for (int i = 0; i < 9; ++i) g[UIDX(i,i)] += ridge;

    // ---- Cholesky: M = L L^T (packed lower tri), linv = 1/diag(L) ----
    double L[45], linv[9];
    #pragma unroll
    for (int i = 0; i < 9; ++i) {
        #pragma unroll
        for (int j = 0; j <= i; ++j) {
            double s = g[UIDX(j,i)];
            #pragma unroll
            for (int t = 0; t < j; ++t) s -= L[LIDX(i,t)] * L[LIDX(j,t)];
            if (j < i) {
                L[LIDX(i,j)] = s * linv[j];
            } else {
                const double d = fmax(s, ridge * 1e-2);  // pivot guard
                const double r = sqrt(d);
                L[LIDX(i,i)] = r;
                linv[i] = 1.0 / r;
            }
        }
    }

    // ---- inverse iteration: x <- normalize((L L^T)^{-1} x) ----
    double x[9];
    #pragma unroll
    for (int j = 0; j < 9; ++j) x[j] = 1.0 + 0.0625 * j;

    #pragma unroll 1
    for (int it = 0; it < NITER; ++it) {
        double y[9];
        #pragma unroll
        for (int i = 0; i < 9; ++i) {
            double s = x[i];
            #pragma unroll
            for (int t = 0; t < i; ++t) s -= L[LIDX(i,t)] * y[t];
            y[i] = s * linv[i];
        }
        double z[9];
        #pragma unroll
        for (int ii = 8; ii >= 0; --ii) {
            double s = y[ii];
            #pragma unroll
            for (int t = 8; t > 0; --t)
                if (t > ii) s -= L[LIDX(t,ii)] * z[t];
            z[ii] = s * linv[ii];
        }
        double n = 0.0;
        #pragma unroll
        for (int j = 0; j < 9; ++j) n += z[j]*z[j];
        const double inv = 1.0 / sqrt(n);
        #pragma unroll
        for (int j = 0; j < 9; ++j) x[j] = z[j] * inv;
    }

    // ---- per-lane masked loss with in-register H = x ----
    double hs = 0.0, hc = 0.0, rs = 0.0, rc = 0.0;
    #pragma unroll
    for (int p = 0; p < 5; ++p) {
        const double px_ = Px[p], py_ = Py[p];
        const double gx = (double)Qgt[(k*5+p)*3 + 0];
        const double gz = (double)Qgt[(k*5+p)*3 + 2];
        const double nw0 = x[0]*px_ + x[1]*py_ + x[2];
        const double nw1 = x[3]*px_ + x[4]*py_ + x[5];
        const double nw2 = x[6]*px_ + x[7]*py_ + x[8];
        const double den = nw2 + 1e-10;
        const double rx = nw0 / den;
        const double rz = nw1 / den;
        const bool msk = (rx > -40.0) && (rx < 40.0) && (rz > 0.0) && (rz < 80.0);
        if (msk) { hs += sl1(rx, gx) + sl1(rz, gz); hc += 2.0; }
        else     { rs += sl1((double)qx[p], gx) + sl1((double)qz[p], gz); rc += 2.0; }
    }

    #pragma unroll
    for (int off = 32; off > 0; off >>= 1) {
        hs += __shfl_xor(hs, off);
        hc += __shfl_xor(hc, off);
        rs += __shfl_xor(rs, off);
        rc += __shfl_xor(rc, off);
    }
    if (m == 0) {
        double* dst = partials + (size_t)(combo*BNUM + b) * 4;
        dst[0] = hs; dst[1] = hc; dst[2] = rs; dst[3] = rc;
    }
}

// Single wave: fold 192x4 partials -> final scalar.
__global__ __launch_bounds__(64) void finalize2(
    const double* __restrict__ partials, float* __restrict__ out)
{
    const int t = threadIdx.x;
    double acc[3][4];
    #pragma unroll
    for (int c = 0; c < 3; ++c)
        #pragma unroll
        for (int j = 0; j < 4; ++j)
            acc[c][j] = partials[(size_t)(c*BNUM + t) * 4 + j];

    #pragma unroll
    for (int off = 32; off > 0; off >>= 1) {
        #pragma unroll
        for (int c = 0; c < 3; ++c)
            #pragma unroll
            for (int j = 0; j < 4; ++j)
                acc[c][j] += __shfl_xor(acc[c][j], off);
    }
    if (t == 0) {
        double tot = 0.0;
        #pragma unroll
        for (int c = 0; c < 3; ++c)
            tot += acc[c][0] / fmax(acc[c][1], 1.0)
                 + 0.5 * (acc[c][2] / fmax(acc[c][3], 1.0));
        out[0] = (float)(tot / 3.0);
    }
}

extern "C" void kernel_launch(void* const* d_in, const int* in_sizes, int n_in,
                              void* d_out, int out_size, void* d_ws, size_t ws_size,
                              hipStream_t stream)
{
    const float* center  = (const float*)d_in[1];
    const int*   cls     = (const int*)  d_in[2];
    const float* ry      = (const float*)d_in[3];
    const float* size3d  = (const float*)d_in[4];
    const float* Pgt     = (const float*)d_in[5];
    const float* Qgt     = (const float*)d_in[6];
    const float* off_gt  = (const float*)d_in[7];
    const float* dep_gt  = (const float*)d_in[8];
    const float* out_off = (const float*)d_in[9];
    const float* out_dep = (const float*)d_in[10];
    const float* calibs  = (const float*)d_in[11];
    const float* tinv    = (const float*)d_in[12];

    double* partials = (double*)d_ws;   // 192*4 doubles
    float*  out      = (float*)d_out;

    fused_kernel<<<dim3(BNUM,3), 64, 0, stream>>>(center, cls, ry, size3d, Pgt, Qgt,
        off_gt, dep_gt, out_off, out_dep, calibs, tinv, partials);
    finalize2<<<1, 64, 0, stream>>>(partials, out);
}